// Round 3
// baseline (326.275 us; speedup 1.0000x reference)
//
#include <hip/hip_runtime.h>

// B=256, N=8192, K=16, fp32 3-point stencil along N:
//   y = x + param
//   out[n] = min(y[n], 0.5*(y[n-1]+y[n+1])) - param[n]   (interior)
//   out[n] = y[n] - param[n] = x[n]                       (n==0, N-1)
//
// v2b: no LDS, no barrier. Each thread owns R_=8 consecutive n-rows of one
// float4 column: 20 independent global loads in flight per thread (vs 2 in
// v1), stencil in registers, non-temporal stores (output is never re-read;
// keep the L3 warm for the inputs). Uses clang ext_vector_type so the
// nontemporal builtin accepts it.

typedef float f32x4 __attribute__((ext_vector_type(4)));

#define B_      256
#define N_      8192
#define KQ      4                 // float4 columns per row (K=16)
#define R_      8                 // rows per thread
#define GROUPS  64                // row-groups per 256-thread block
#define TILE    (GROUPS * R_)     // 512 rows per block
#define TILES_N (N_ / TILE)       // 16

__global__ __launch_bounds__(256)
void convex_kernel(const f32x4* __restrict__ x4,
                   const f32x4* __restrict__ p4,
                   f32x4* __restrict__ o4)
{
    const int tid = threadIdx.x;
    const int g   = tid >> 2;               // row-group 0..63
    const int c   = tid & 3;                // float4 column 0..3
    const int t   = blockIdx.x & (TILES_N - 1);
    const int b   = blockIdx.x >> 4;        // TILES_N == 16
    const int n0  = t * TILE + g * R_;      // first output row of this thread
    const long rowbase = (long)b * N_;      // row index of batch origin

    // Load rows n0-1 .. n0+R_ of x and param. Clamp at the array ends —
    // the clamped (bogus) halo values only ever feed rows 0 / N-1, which
    // take the boundary path (out = x) and ignore them.
    f32x4 xv[R_ + 2], pv[R_ + 2];
#pragma unroll
    for (int j = 0; j < R_ + 2; ++j) {
        int row = n0 - 1 + j;
        row = row < 0 ? 0 : row;
        row = row > N_ - 1 ? N_ - 1 : row;
        const long idx = (rowbase + row) * KQ + c;
        xv[j] = x4[idx];
        pv[j] = p4[idx];
    }

#pragma unroll
    for (int j = 0; j < R_; ++j) {
        const int n = n0 + j;
        f32x4 r;
        if (n == 0 || n == N_ - 1) {
            // out = y - param = x exactly
            r = xv[j + 1];
        } else {
            const f32x4 ym = xv[j]     + pv[j];       // y[n-1]
            const f32x4 yc = xv[j + 1] + pv[j + 1];   // y[n]
            const f32x4 yp = xv[j + 2] + pv[j + 2];   // y[n+1]
            const f32x4 m  = 0.5f * (ym + yp);
            f32x4 mn;
            mn.x = fminf(yc.x, m.x);
            mn.y = fminf(yc.y, m.y);
            mn.z = fminf(yc.z, m.z);
            mn.w = fminf(yc.w, m.w);
            r = mn - pv[j + 1];
        }
        __builtin_nontemporal_store(r, &o4[(rowbase + n) * KQ + c]);
    }
}

extern "C" void kernel_launch(void* const* d_in, const int* in_sizes, int n_in,
                              void* d_out, int out_size, void* d_ws, size_t ws_size,
                              hipStream_t stream)
{
    const f32x4* x = (const f32x4*)d_in[0];
    const f32x4* p = (const f32x4*)d_in[1];
    f32x4*       o = (f32x4*)d_out;

    dim3 grid(B_ * TILES_N);   // 4096 blocks
    dim3 block(256);
    convex_kernel<<<grid, block, 0, stream>>>(x, p, o);
}

// Round 4
// 323.298 us; speedup vs baseline: 1.0092x; 1.0092x over previous
//
#include <hip/hip_runtime.h>

// B=256, N=8192, K=16, fp32 3-point stencil along N:
//   y = x + param
//   out[n] = min(y[n], 0.5*(y[n-1]+y[n+1])) - param[n]   (interior)
//   out[n] = y[n] - param[n]                              (n==0, N-1)
//
// v3: rolling-wave structure. Each wave owns SPAN=256 consecutive rows and
// walks them in 16-row chunks; one chunk = one contiguous aligned 1 KiB
// load/store per instruction (perfect coalescing, unlike v2b's 64B-granule
// scatter). Row +/-1 neighbors = lane +/-4 via __shfl; chunk-edge neighbors
// carried in registers (y_prev / y_next). x,p read exactly once; no LDS, no
// barrier; next-chunk loads issued one iteration early for MLP. NT stores
// are full-line here, so no write amplification.

typedef float f32x4 __attribute__((ext_vector_type(4)));

#define B_    256
#define N_    8192
#define KQ    4                // f32x4 per row (K=16)
#define CH    16               // rows per chunk (64 lanes / 4 cols)
#define SPAN  256              // rows per wave
#define M_    (SPAN / CH)      // 16 chunks per wave
#define WPB   4                // waves per block
#define SPB   (N_ / SPAN)      // 32 spans per batch

__device__ __forceinline__ f32x4 shfl4(f32x4 v, int src) {
    f32x4 r;
    r.x = __shfl(v.x, src);
    r.y = __shfl(v.y, src);
    r.z = __shfl(v.z, src);
    r.w = __shfl(v.w, src);
    return r;
}

__global__ __launch_bounds__(256)
void convex_kernel(const f32x4* __restrict__ x4,
                   const f32x4* __restrict__ p4,
                   f32x4* __restrict__ o4)
{
    const int tid  = threadIdx.x;
    const int lane = tid & 63;
    const int wv   = tid >> 6;
    const int gw   = blockIdx.x * WPB + wv;   // global wave id, 0..8191
    const int b    = gw >> 5;                 // batch (SPB == 32)
    const int s    = (gw & 31) * SPAN;        // first row of this wave's span
    const int lr   = lane >> 2;               // local row 0..15
    const int c    = lane & 3;                // f32x4 column 0..3

    const long batch = (long)b * N_ * KQ;     // f32x4 index of batch origin

    // ---- prologue: edge rows (broadcast loads, one 64B fetch each) ----
    // up-edge row s-1 -> lanes 60..63 of y_prev (their c = 0..3).
    // If s==0 the value is garbage but only feeds row 0, which takes the
    // boundary path.
    const int rup = (s - 1 < 0) ? 0 : s - 1;
    const int rdn = (s + SPAN > N_ - 1) ? N_ - 1 : s + SPAN;
    f32x4 y_prev, y_edge_dn;
    {
        long i = batch + (long)rup * KQ + c;
        y_prev = x4[i] + p4[i];               // meaningful in lanes 60..63
    }
    {
        long i = batch + (long)rdn * KQ + c;
        y_edge_dn = x4[i] + p4[i];            // meaningful in lanes 0..3
    }

    // ---- chunk 0 ----
    long idx = batch + (long)(s + lr) * KQ + c;
    f32x4 p_c = p4[idx];
    f32x4 y_cur = x4[idx] + p_c;

    const int idx_up = (lane + 60) & 63;      // == lane-4 for lane>=4
    const int idx_dn = (lane + 4) & 63;       // == lane-60 for lane>=60
    const bool lo = (lane < 4);
    const bool hi = (lane >= 60);

    f32x4 p_n = p_c, y_next;

#pragma unroll 2
    for (int j = 0; j < M_; ++j) {
        if (j < M_ - 1) {                     // wave-uniform branch
            const long ni = idx + CH * KQ;
            f32x4 xn = x4[ni];                // issued one iter ahead of use
            p_n = p4[ni];
            y_next = xn + p_n;
        } else {
            y_next = y_edge_dn;
        }

        const f32x4 up_c = shfl4(y_cur,  idx_up);
        const f32x4 up_p = shfl4(y_prev, idx_up);
        const f32x4 dn_c = shfl4(y_cur,  idx_dn);
        const f32x4 dn_n = shfl4(y_next, idx_dn);
        const f32x4 up = lo ? up_p : up_c;    // row n-1
        const f32x4 dn = hi ? dn_n : dn_c;    // row n+1

        const f32x4 mid = 0.5f * (up + dn);
        f32x4 mn;
        mn.x = fminf(y_cur.x, mid.x);
        mn.y = fminf(y_cur.y, mid.y);
        mn.z = fminf(y_cur.z, mid.z);
        mn.w = fminf(y_cur.w, mid.w);

        const int n = s + j * CH + lr;
        if (n == 0 || n == N_ - 1) mn = y_cur;   // boundary: out = y - p

        __builtin_nontemporal_store(mn - p_c, &o4[idx]);

        // rotate pipeline state
        y_prev = y_cur;
        y_cur  = y_next;
        p_c    = p_n;
        idx   += CH * KQ;
    }
}

extern "C" void kernel_launch(void* const* d_in, const int* in_sizes, int n_in,
                              void* d_out, int out_size, void* d_ws, size_t ws_size,
                              hipStream_t stream)
{
    const f32x4* x = (const f32x4*)d_in[0];
    const f32x4* p = (const f32x4*)d_in[1];
    f32x4*       o = (f32x4*)d_out;

    dim3 grid(B_ * SPB / WPB);   // 2048 blocks x 256 threads = 8192 waves
    dim3 block(256);
    convex_kernel<<<grid, block, 0, stream>>>(x, p, o);
}